// Round 2
// baseline (5310.355 us; speedup 1.0000x reference)
//
#include <hip/hip_runtime.h>
#include <math.h>

#define F 1024
#define BM 128
#define BN 128
#define BK 32

typedef short s2 __attribute__((ext_vector_type(2)));
typedef short s4 __attribute__((ext_vector_type(4)));
typedef short s8 __attribute__((ext_vector_type(8)));
typedef float v4f __attribute__((ext_vector_type(4)));

#define SCALE 1024.0f
#define ISCALE (1.0f / 1024.0f)

// d.lo = a.lo + b.lo ; d.hi = a.lo + b.hi   (broadcast a.lo across both halves)
static __device__ __forceinline__ s2 pk_add_blo(s2 a, s2 b) {
  s2 d;
  asm("v_pk_add_i16 %0, %1, %2 op_sel:[0,0] op_sel_hi:[0,1]" : "=v"(d) : "v"(a), "v"(b));
  return d;
}
// d.lo = a.hi + b.lo ; d.hi = a.hi + b.hi   (broadcast a.hi across both halves)
static __device__ __forceinline__ s2 pk_add_bhi(s2 a, s2 b) {
  s2 d;
  asm("v_pk_add_i16 %0, %1, %2 op_sel:[1,0] op_sel_hi:[1,1]" : "=v"(d) : "v"(a), "v"(b));
  return d;
}
static __device__ __forceinline__ s2 pk_max_i16(s2 a, s2 b) {
  return __builtin_elementwise_max(a, b);  // v_pk_max_i16, compiler-scheduled
}

// quantize f32 -> i16 at SCALE, clamped (clamps unreachable for real data; they
// only guarantee no i16 add overflow: 28000 + 4700 < 32767)
static __device__ __forceinline__ short q_i16(float v, float clampv) {
  return (short)__float2int_rn(fminf(fmaxf(v * SCALE, -clampv), clampv));
}

// ---------------- LayerNorm: one WAVE per row, i16(x1024) out ----------------
__global__ __launch_bounds__(256) void ln_kernel(const float* __restrict__ x,
                                                 const float* __restrict__ gamma,
                                                 const float* __restrict__ beta,
                                                 short* __restrict__ xn) {
  const int lane = threadIdx.x & 63;
  const int wv = threadIdx.x >> 6;
  const int row = blockIdx.x * 4 + wv;
  const float4* xr = (const float4*)(x + (size_t)row * F);
  float4 v[4];
  float s = 0.f;
#pragma unroll
  for (int j = 0; j < 4; ++j) {
    v[j] = xr[lane + 64 * j];
    s += v[j].x + v[j].y + v[j].z + v[j].w;
  }
#pragma unroll
  for (int off = 32; off; off >>= 1) s += __shfl_xor(s, off, 64);
  const float mu = s * (1.0f / F);
  float sq = 0.f;
#pragma unroll
  for (int j = 0; j < 4; ++j) {
    v[j].x -= mu; v[j].y -= mu; v[j].z -= mu; v[j].w -= mu;
    sq += v[j].x * v[j].x + v[j].y * v[j].y + v[j].z * v[j].z + v[j].w * v[j].w;
  }
#pragma unroll
  for (int off = 32; off; off >>= 1) sq += __shfl_xor(sq, off, 64);
  const float r = rsqrtf(sq * (1.0f / F) + 1e-5f);
  const float4* g4 = (const float4*)gamma;
  const float4* b4 = (const float4*)beta;
  s4* o = (s4*)(xn + (size_t)row * F);
#pragma unroll
  for (int j = 0; j < 4; ++j) {
    const int idx = lane + 64 * j;
    const float4 g = g4[idx];
    const float4 bb = b4[idx];
    s4 q;
    q[0] = q_i16(v[j].x * r * g.x + bb.x, 28000.f);
    q[1] = q_i16(v[j].y * r * g.y + bb.y, 28000.f);
    q[2] = q_i16(v[j].z * r * g.z + bb.z, 28000.f);
    q[3] = q_i16(v[j].w * r * g.w + bb.w, 28000.f);
    o[idx] = q;
  }
}

// ---------------- W: f32 -> i16(x1024) ----------------
__global__ __launch_bounds__(256) void cvt_kernel(const float* __restrict__ Wf,
                                                  short* __restrict__ Wq) {
  const int i = blockIdx.x * 256 + threadIdx.x;  // float4 index
  const float4 v = ((const float4*)Wf)[i];
  s4 q;
  q[0] = q_i16(v.x, 4700.f);
  q[1] = q_i16(v.y, 4700.f);
  q[2] = q_i16(v.z, 4700.f);
  q[3] = q_i16(v.w, 4700.f);
  ((s4*)Wq)[i] = q;
}

// ---------------- i16 packed tropical (max,+) GEMM ----------------
// 1 VALU instr per update (v_pk_add_i16 w/ op_sel broadcast + v_pk_max_i16).
// BK=32 (1 barrier / 32 k), explicit 1-deep register pipeline on the LDS reads
// so the ~120cyc ds_read latency hides under each k's 64-instr compute.
__global__ __launch_bounds__(256, 4) void trop_i(const short* __restrict__ A,
                                                 const short* __restrict__ Wm,
                                                 const float* __restrict__ bias,
                                                 short* __restrict__ dsts,
                                                 float* __restrict__ outf,
                                                 int ntiles, int totrows, int fuse) {
  __shared__ alignas(16) short As[2][BK][BM];  // transposed: As[buf][k][m]
  __shared__ alignas(16) short Bs[2][BK][BN];  // Bs[buf][k][n]

  const int tid = threadIdx.x;
  const int tx = tid & 15;
  const int ty = tid >> 4;
  const int row0 = blockIdx.y * BM;
  const int col0 = blockIdx.x * BN;
  const int kbase = blockIdx.z * ntiles * BK;

  // A stage: thread -> (row ar, k-half ak), 2x s8 loads, 16 scalar LDS writes
  const int ar = tid & 127;
  const int ak = (tid >> 7) << 4;    // 0 or 16
  // B stage: one k-row per 8 threads, 2x s8 load/store
  const int bk = tid >> 3;           // 0..31
  const int bn = (tid & 7) << 4;     // 0,16,...,112

  const short* Arow = A + (size_t)(row0 + ar) * F + kbase + ak;
  const short* Wrow = Wm + (size_t)(kbase + bk) * F + col0 + bn;

  s2 acc[8][4];
  const s2 ninf = {(short)-32768, (short)-32768};
#pragma unroll
  for (int m = 0; m < 8; ++m)
#pragma unroll
    for (int n = 0; n < 4; ++n) acc[m][n] = ninf;

  // stage tile 0 into buf 0
  {
    const s8 av0 = *(const s8*)Arow;
    const s8 av1 = *(const s8*)(Arow + 8);
    const s8 bv0 = *(const s8*)Wrow;
    const s8 bv1 = *(const s8*)(Wrow + 8);
#pragma unroll
    for (int j = 0; j < 8; ++j) {
      As[0][ak + j][ar] = av0[j];
      As[0][ak + 8 + j][ar] = av1[j];
    }
    *(s8*)&Bs[0][bk][bn] = bv0;
    *(s8*)&Bs[0][bk][bn + 8] = bv1;
  }
  __syncthreads();

  for (int kt = 0; kt < ntiles; ++kt) {
    const int cur = kt & 1;
    s8 av0, av1, bv0, bv1;
    if (kt + 1 < ntiles) {
      const short* An = Arow + (kt + 1) * BK;
      const short* Bn = Wrow + (size_t)(kt + 1) * BK * F;
      av0 = *(const s8*)An;
      av1 = *(const s8*)(An + 8);
      bv0 = *(const s8*)Bn;
      bv1 = *(const s8*)(Bn + 8);
    }

    // register-pipelined k loop: issue k+1's LDS reads before computing k
    s8 a_c = *(const s8*)&As[cur][0][ty * 8];
    s8 b_c = *(const s8*)&Bs[cur][0][tx * 8];
#pragma unroll
    for (int k = 0; k < BK; ++k) {
      s8 a_n, b_n;
      if (k + 1 < BK) {
        a_n = *(const s8*)&As[cur][k + 1][ty * 8];
        b_n = *(const s8*)&Bs[cur][k + 1][tx * 8];
      }
      const s2* a2 = (const s2*)&a_c;
      const s2* b2 = (const s2*)&b_c;
#pragma unroll
      for (int m = 0; m < 8; ++m) {
        const s2 am = a2[m >> 1];
#pragma unroll
        for (int nn = 0; nn < 4; ++nn) {
          const s2 t = (m & 1) ? pk_add_bhi(am, b2[nn]) : pk_add_blo(am, b2[nn]);
          acc[m][nn] = pk_max_i16(acc[m][nn], t);
        }
      }
      a_c = a_n;
      b_c = b_n;
    }

    if (kt + 1 < ntiles) {
      const int nxt = cur ^ 1;
#pragma unroll
      for (int j = 0; j < 8; ++j) {
        As[nxt][ak + j][ar] = av0[j];
        As[nxt][ak + 8 + j][ar] = av1[j];
      }
      *(s8*)&Bs[nxt][bk][bn] = bv0;
      *(s8*)&Bs[nxt][bk][bn + 8] = bv1;
      __syncthreads();
    }
  }

  if (fuse) {
    const float4 bv0 = *(const float4*)(bias + col0 + tx * 8);
    const float4 bv1 = *(const float4*)(bias + col0 + tx * 8 + 4);
#pragma unroll
    for (int m = 0; m < 8; ++m) {
      float* orow = outf + (size_t)(row0 + ty * 8 + m) * F + col0 + tx * 8;
      float4 o0, o1;
      o0.x = fmaxf((float)acc[m][0][0] * ISCALE, bv0.x);
      o0.y = fmaxf((float)acc[m][0][1] * ISCALE, bv0.y);
      o0.z = fmaxf((float)acc[m][1][0] * ISCALE, bv0.z);
      o0.w = fmaxf((float)acc[m][1][1] * ISCALE, bv0.w);
      o1.x = fmaxf((float)acc[m][2][0] * ISCALE, bv1.x);
      o1.y = fmaxf((float)acc[m][2][1] * ISCALE, bv1.y);
      o1.z = fmaxf((float)acc[m][3][0] * ISCALE, bv1.z);
      o1.w = fmaxf((float)acc[m][3][1] * ISCALE, bv1.w);
      *(float4*)orow = o0;
      *(float4*)(orow + 4) = o1;
    }
  } else {
    short* base = dsts + (size_t)blockIdx.z * totrows * F;
#pragma unroll
    for (int m = 0; m < 8; ++m) {
      short* orow = base + (size_t)(row0 + ty * 8 + m) * F + col0 + tx * 8;
      s8 o;
#pragma unroll
      for (int nn = 0; nn < 4; ++nn) {
        o[2 * nn] = acc[m][nn][0];
        o[2 * nn + 1] = acc[m][nn][1];
      }
      *(s8*)orow = o;
    }
  }
}

// ---------------- combine: out = max(NP i16 partials)/1024, then max(bias) ----------------
template <int NP>
__global__ __launch_bounds__(256) void combineNs(const short* __restrict__ p,
                                                 size_t plane,
                                                 const float* __restrict__ bias,
                                                 float* __restrict__ out) {
  const int i = blockIdx.x * 256 + threadIdx.x;  // s8 index
  s8 v = ((const s8*)p)[i];
  s2* vv = (s2*)&v;
#pragma unroll
  for (int q = 1; q < NP; ++q) {
    const s8 u = ((const s8*)(p + (size_t)q * plane))[i];
    const s2* uu = (const s2*)&u;
#pragma unroll
    for (int j = 0; j < 4; ++j) vv[j] = pk_max_i16(vv[j], uu[j]);
  }
  const int nb = (i & (F / 8 - 1)) * 8;
  const v4f bb0 = *(const v4f*)(bias + nb);
  const v4f bb1 = *(const v4f*)(bias + nb + 4);
  float4* o4 = (float4*)(out + (size_t)i * 8);
  float4 o0, o1;
  o0.x = fmaxf((float)v[0] * ISCALE, bb0.x);
  o0.y = fmaxf((float)v[1] * ISCALE, bb0.y);
  o0.z = fmaxf((float)v[2] * ISCALE, bb0.z);
  o0.w = fmaxf((float)v[3] * ISCALE, bb0.w);
  o1.x = fmaxf((float)v[4] * ISCALE, bb1.x);
  o1.y = fmaxf((float)v[5] * ISCALE, bb1.y);
  o1.z = fmaxf((float)v[6] * ISCALE, bb1.z);
  o1.w = fmaxf((float)v[7] * ISCALE, bb1.w);
  o4[0] = o0;
  o4[1] = o1;
}

extern "C" void kernel_launch(void* const* d_in, const int* in_sizes, int n_in,
                              void* d_out, int out_size, void* d_ws, size_t ws_size,
                              hipStream_t stream) {
  const float* x = (const float*)d_in[0];
  const float* Wm = (const float*)d_in[1];
  const float* bias = (const float*)d_in[2];
  const float* gamma = (const float*)d_in[3];
  const float* beta = (const float*)d_in[4];
  float* out = (float*)d_out;

  const int Brows = in_sizes[0] / F;  // 4096
  const size_t plane = (size_t)Brows * F;

  short* xnq = (short*)d_ws;                     // plane i16 (8 MB)
  short* Wq = xnq + plane;                       // F*F i16 (2 MB)
  short* parts = Wq + (size_t)F * F;             // 4 planes i16 (32 MB)

  ln_kernel<<<Brows / 4, 256, 0, stream>>>(x, gamma, beta, xnq);
  cvt_kernel<<<(F * F) / 1024, 256, 0, stream>>>(Wm, Wq);

  const size_t need4 = plane * 2 + (size_t)F * F * 2 + 4 * plane * 2;
  const size_t need1 = plane * 2 + (size_t)F * F * 2;
  if (ws_size >= need4) {
    dim3 grid(F / BN, Brows / BM, 4);  // 1024 blocks = 4 blocks/CU
    trop_i<<<grid, 256, 0, stream>>>(xnq, Wq, bias, parts, nullptr,
                                     (F / BK) / 4, Brows, 0);
    combineNs<4><<<(int)(plane / 2048), 256, 0, stream>>>(parts, plane, bias, out);
  } else if (ws_size >= need1) {
    dim3 grid(F / BN, Brows / BM, 1);
    trop_i<<<grid, 256, 0, stream>>>(xnq, Wq, bias, nullptr, out, F / BK, Brows, 1);
  }
}

// Round 3
// 234.578 us; speedup vs baseline: 22.6379x; 22.6379x over previous
//
#include <hip/hip_runtime.h>
#include <math.h>

#define F 1024
#define BM 128
#define BN 128
#define BK 16

typedef short s2 __attribute__((ext_vector_type(2)));
typedef short s4 __attribute__((ext_vector_type(4)));
typedef short s8 __attribute__((ext_vector_type(8)));
typedef float v4f __attribute__((ext_vector_type(4)));

#define SCALE 1024.0f
#define ISCALE (1.0f / 1024.0f)

static __device__ __forceinline__ s2 pk_max_i16(s2 a, s2 b) {
  s2 d;
  asm("v_pk_max_i16 %0, %1, %2" : "=v"(d) : "v"(a), "v"(b));
  return d;
}
// d.lo = a.lo + b.lo ; d.hi = a.lo + b.hi   (broadcast a.lo across both halves)
static __device__ __forceinline__ s2 pk_add_blo(s2 a, s2 b) {
  s2 d;
  asm("v_pk_add_i16 %0, %1, %2 op_sel:[0,0] op_sel_hi:[0,1]" : "=v"(d) : "v"(a), "v"(b));
  return d;
}
// d.lo = a.hi + b.lo ; d.hi = a.hi + b.hi   (broadcast a.hi across both halves)
static __device__ __forceinline__ s2 pk_add_bhi(s2 a, s2 b) {
  s2 d;
  asm("v_pk_add_i16 %0, %1, %2 op_sel:[1,0] op_sel_hi:[1,1]" : "=v"(d) : "v"(a), "v"(b));
  return d;
}

// quantize f32 -> i16 at SCALE, clamped (clamps unreachable for real data; they
// only guarantee no i16 add overflow: 28000 + 4700 < 32767)
static __device__ __forceinline__ short q_i16(float v, float clampv) {
  return (short)__float2int_rn(fminf(fmaxf(v * SCALE, -clampv), clampv));
}

// ---------------- LayerNorm: one WAVE per row, i16(x1024) out ----------------
__global__ __launch_bounds__(256) void ln_kernel(const float* __restrict__ x,
                                                 const float* __restrict__ gamma,
                                                 const float* __restrict__ beta,
                                                 short* __restrict__ xn) {
  const int lane = threadIdx.x & 63;
  const int wv = threadIdx.x >> 6;
  const int row = blockIdx.x * 4 + wv;
  const float4* xr = (const float4*)(x + (size_t)row * F);
  float4 v[4];
  float s = 0.f;
#pragma unroll
  for (int j = 0; j < 4; ++j) {
    v[j] = xr[lane + 64 * j];
    s += v[j].x + v[j].y + v[j].z + v[j].w;
  }
#pragma unroll
  for (int off = 32; off; off >>= 1) s += __shfl_xor(s, off, 64);
  const float mu = s * (1.0f / F);
  float sq = 0.f;
#pragma unroll
  for (int j = 0; j < 4; ++j) {
    v[j].x -= mu; v[j].y -= mu; v[j].z -= mu; v[j].w -= mu;
    sq += v[j].x * v[j].x + v[j].y * v[j].y + v[j].z * v[j].z + v[j].w * v[j].w;
  }
#pragma unroll
  for (int off = 32; off; off >>= 1) sq += __shfl_xor(sq, off, 64);
  const float r = rsqrtf(sq * (1.0f / F) + 1e-5f);
  const float4* g4 = (const float4*)gamma;
  const float4* b4 = (const float4*)beta;
  s4* o = (s4*)(xn + (size_t)row * F);
#pragma unroll
  for (int j = 0; j < 4; ++j) {
    const int idx = lane + 64 * j;
    const float4 g = g4[idx];
    const float4 bb = b4[idx];
    s4 q;
    q[0] = q_i16(v[j].x * r * g.x + bb.x, 28000.f);
    q[1] = q_i16(v[j].y * r * g.y + bb.y, 28000.f);
    q[2] = q_i16(v[j].z * r * g.z + bb.z, 28000.f);
    q[3] = q_i16(v[j].w * r * g.w + bb.w, 28000.f);
    o[idx] = q;
  }
}

// ---------------- W: f32 -> i16(x1024) ----------------
__global__ __launch_bounds__(256) void cvt_kernel(const float* __restrict__ Wf,
                                                  short* __restrict__ Wq) {
  const int i = blockIdx.x * 256 + threadIdx.x;  // float4 index
  const float4 v = ((const float4*)Wf)[i];
  s4 q;
  q[0] = q_i16(v.x, 4700.f);
  q[1] = q_i16(v.y, 4700.f);
  q[2] = q_i16(v.z, 4700.f);
  q[3] = q_i16(v.w, 4700.f);
  ((s4*)Wq)[i] = q;
}

// ---------------- i16 packed tropical (max,+) GEMM: 1 instr/update ----------------
// Thread (tx,ty): rows ty*8..+7, cols tx*8..+7. acc[m][nn] = i16x2 covering cols
// {tx*8+2nn, +1}. Inner per k per (m,nn): v_pk_add_i16 (op_sel bcast) + v_pk_max_i16
// -> 2 instrs / 2 updates. LDS: 1 ds_read_b128 for A + 1 for B per k per thread.
// R3: latency hiding via TLP, not ILP (R2's source pipeline spilled to scratch).
// launch_bounds(256,8) + 8 blocks/CU from split-K z=8: 32 waves/CU.
__global__ __launch_bounds__(256, 8) void trop_i(const short* __restrict__ A,
                                                 const short* __restrict__ Wm,
                                                 const float* __restrict__ bias,
                                                 short* __restrict__ dsts,
                                                 float* __restrict__ outf,
                                                 int ntiles, int totrows, int fuse) {
  __shared__ alignas(16) short As[2][BK][BM];  // transposed: As[buf][k][m]
  __shared__ alignas(16) short Bs[2][BK][BN];  // Bs[buf][k][n]

  const int tid = threadIdx.x;
  const int tx = tid & 15;
  const int ty = tid >> 4;
  const int row0 = blockIdx.y * BM;
  const int col0 = blockIdx.x * BN;
  const int kbase = blockIdx.z * ntiles * BK;

  // A stage: lane -> row (contiguous-in-m LDS writes: 2-way bank = free)
  const int ar = tid & 127;          // row 0..127
  const int ak = (tid >> 7) << 3;    // k offset 0 or 8
  // B stage: one k-row per 16 threads, contiguous 256B per k-row
  const int bk = tid >> 4;           // k-row 0..15
  const int bn = (tid & 15) << 3;    // col offset

  const short* Arow = A + (size_t)(row0 + ar) * F + kbase + ak;
  const short* Wrow = Wm + (size_t)(kbase + bk) * F + col0 + bn;

  s2 acc[8][4];
  const s2 ninf = {(short)-32768, (short)-32768};
#pragma unroll
  for (int m = 0; m < 8; ++m)
#pragma unroll
    for (int n = 0; n < 4; ++n) acc[m][n] = ninf;

  // stage tile 0 into buf 0
  {
    const s8 av = *(const s8*)Arow;
    const s8 bv = *(const s8*)Wrow;
#pragma unroll
    for (int j = 0; j < 8; ++j) As[0][ak + j][ar] = av[j];
    *(s8*)&Bs[0][bk][bn] = bv;
  }
  __syncthreads();

  for (int kt = 0; kt < ntiles; ++kt) {
    const int cur = kt & 1;
    s8 av, bv;
    if (kt + 1 < ntiles) {
      av = *(const s8*)(Arow + (kt + 1) * BK);
      bv = *(const s8*)(Wrow + (size_t)(kt + 1) * BK * F);
    }

#pragma unroll
    for (int k = 0; k < BK; ++k) {
      s8 a = *(const s8*)&As[cur][k][ty * 8];  // 8 rows
      s8 b = *(const s8*)&Bs[cur][k][tx * 8];  // 8 cols
      const s2* a2 = (const s2*)&a;
      const s2* b2 = (const s2*)&b;
#pragma unroll
      for (int m = 0; m < 8; ++m) {
        const s2 am = a2[m >> 1];
#pragma unroll
        for (int nn = 0; nn < 4; ++nn) {
          const s2 t = (m & 1) ? pk_add_bhi(am, b2[nn]) : pk_add_blo(am, b2[nn]);
          acc[m][nn] = pk_max_i16(acc[m][nn], t);
        }
      }
    }

    if (kt + 1 < ntiles) {
      const int nxt = cur ^ 1;
#pragma unroll
      for (int j = 0; j < 8; ++j) As[nxt][ak + j][ar] = av[j];
      *(s8*)&Bs[nxt][bk][bn] = bv;
      __syncthreads();
    }
  }

  if (fuse) {
    const float4 bv0 = *(const float4*)(bias + col0 + tx * 8);
    const float4 bv1 = *(const float4*)(bias + col0 + tx * 8 + 4);
#pragma unroll
    for (int m = 0; m < 8; ++m) {
      float* orow = outf + (size_t)(row0 + ty * 8 + m) * F + col0 + tx * 8;
      float4 o0, o1;
      o0.x = fmaxf((float)acc[m][0][0] * ISCALE, bv0.x);
      o0.y = fmaxf((float)acc[m][0][1] * ISCALE, bv0.y);
      o0.z = fmaxf((float)acc[m][1][0] * ISCALE, bv0.z);
      o0.w = fmaxf((float)acc[m][1][1] * ISCALE, bv0.w);
      o1.x = fmaxf((float)acc[m][2][0] * ISCALE, bv1.x);
      o1.y = fmaxf((float)acc[m][2][1] * ISCALE, bv1.y);
      o1.z = fmaxf((float)acc[m][3][0] * ISCALE, bv1.z);
      o1.w = fmaxf((float)acc[m][3][1] * ISCALE, bv1.w);
      *(float4*)orow = o0;
      *(float4*)(orow + 4) = o1;
    }
  } else {
    short* base = dsts + (size_t)blockIdx.z * totrows * F;
#pragma unroll
    for (int m = 0; m < 8; ++m) {
      short* orow = base + (size_t)(row0 + ty * 8 + m) * F + col0 + tx * 8;
      s8 o;
#pragma unroll
      for (int nn = 0; nn < 4; ++nn) {
        o[2 * nn] = acc[m][nn][0];
        o[2 * nn + 1] = acc[m][nn][1];
      }
      *(s8*)orow = o;
    }
  }
}

// ---------------- combine: out = max(NP i16 partials)/1024, then max(bias) ----------------
template <int NP>
__global__ __launch_bounds__(256) void combineNs(const short* __restrict__ p,
                                                 size_t plane,
                                                 const float* __restrict__ bias,
                                                 float* __restrict__ out) {
  const int i = blockIdx.x * 256 + threadIdx.x;  // s8 index
  s8 v = ((const s8*)p)[i];
  s2* vv = (s2*)&v;
#pragma unroll
  for (int q = 1; q < NP; ++q) {
    const s8 u = ((const s8*)(p + (size_t)q * plane))[i];
    const s2* uu = (const s2*)&u;
#pragma unroll
    for (int j = 0; j < 4; ++j) vv[j] = pk_max_i16(vv[j], uu[j]);
  }
  const int nb = (i & (F / 8 - 1)) * 8;
  const v4f bb0 = *(const v4f*)(bias + nb);
  const v4f bb1 = *(const v4f*)(bias + nb + 4);
  float4* o4 = (float4*)(out + (size_t)i * 8);
  float4 o0, o1;
  o0.x = fmaxf((float)v[0] * ISCALE, bb0.x);
  o0.y = fmaxf((float)v[1] * ISCALE, bb0.y);
  o0.z = fmaxf((float)v[2] * ISCALE, bb0.z);
  o0.w = fmaxf((float)v[3] * ISCALE, bb0.w);
  o1.x = fmaxf((float)v[4] * ISCALE, bb1.x);
  o1.y = fmaxf((float)v[5] * ISCALE, bb1.y);
  o1.z = fmaxf((float)v[6] * ISCALE, bb1.z);
  o1.w = fmaxf((float)v[7] * ISCALE, bb1.w);
  o4[0] = o0;
  o4[1] = o1;
}

extern "C" void kernel_launch(void* const* d_in, const int* in_sizes, int n_in,
                              void* d_out, int out_size, void* d_ws, size_t ws_size,
                              hipStream_t stream) {
  const float* x = (const float*)d_in[0];
  const float* Wm = (const float*)d_in[1];
  const float* bias = (const float*)d_in[2];
  const float* gamma = (const float*)d_in[3];
  const float* beta = (const float*)d_in[4];
  float* out = (float*)d_out;

  const int Brows = in_sizes[0] / F;  // 4096
  const size_t plane = (size_t)Brows * F;

  short* xnq = (short*)d_ws;                     // plane i16 (8 MB)
  short* Wq = xnq + plane;                       // F*F i16 (2 MB)
  short* parts = Wq + (size_t)F * F;             // up to 8 planes i16 (64 MB)

  ln_kernel<<<Brows / 4, 256, 0, stream>>>(x, gamma, beta, xnq);
  cvt_kernel<<<(F * F) / 1024, 256, 0, stream>>>(Wm, Wq);

  const size_t base2 = plane * 2 + (size_t)F * F * 2;
  const size_t need8 = base2 + 8 * plane * 2;
  const size_t need4 = base2 + 4 * plane * 2;
  const size_t need1 = base2;
  if (ws_size >= need8) {
    dim3 grid(F / BN, Brows / BM, 8);  // 2048 blocks = 8 blocks/CU = 32 waves/CU
    trop_i<<<grid, 256, 0, stream>>>(xnq, Wq, bias, parts, nullptr,
                                     (F / BK) / 8, Brows, 0);
    combineNs<8><<<(int)(plane / 2048), 256, 0, stream>>>(parts, plane, bias, out);
  } else if (ws_size >= need4) {
    dim3 grid(F / BN, Brows / BM, 4);  // 1024 blocks = 4 blocks/CU
    trop_i<<<grid, 256, 0, stream>>>(xnq, Wq, bias, parts, nullptr,
                                     (F / BK) / 4, Brows, 0);
    combineNs<4><<<(int)(plane / 2048), 256, 0, stream>>>(parts, plane, bias, out);
  } else if (ws_size >= need1) {
    dim3 grid(F / BN, Brows / BM, 1);
    trop_i<<<grid, 256, 0, stream>>>(xnq, Wq, bias, nullptr, out, F / BK, Brows, 1);
  }
}

// Round 4
// 220.235 us; speedup vs baseline: 24.1122x; 1.0651x over previous
//
#include <hip/hip_runtime.h>
#include <math.h>

#define F 1024
#define BM 128
#define BN 128
#define BK 16

typedef short s2 __attribute__((ext_vector_type(2)));
typedef short s4 __attribute__((ext_vector_type(4)));
typedef short s8 __attribute__((ext_vector_type(8)));
typedef float v4f __attribute__((ext_vector_type(4)));

#define SCALE 1024.0f
#define ISCALE (1.0f / 1024.0f)

static __device__ __forceinline__ s2 pk_max_i16(s2 a, s2 b) {
  s2 d;
  asm("v_pk_max_i16 %0, %1, %2" : "=v"(d) : "v"(a), "v"(b));
  return d;
}
// d.lo = a.lo + b.lo ; d.hi = a.lo + b.hi   (broadcast a.lo across both halves)
static __device__ __forceinline__ s2 pk_add_blo(s2 a, s2 b) {
  s2 d;
  asm("v_pk_add_i16 %0, %1, %2 op_sel:[0,0] op_sel_hi:[0,1]" : "=v"(d) : "v"(a), "v"(b));
  return d;
}
// d.lo = a.hi + b.lo ; d.hi = a.hi + b.hi   (broadcast a.hi across both halves)
static __device__ __forceinline__ s2 pk_add_bhi(s2 a, s2 b) {
  s2 d;
  asm("v_pk_add_i16 %0, %1, %2 op_sel:[1,0] op_sel_hi:[1,1]" : "=v"(d) : "v"(a), "v"(b));
  return d;
}

// quantize f32 -> i16 at SCALE, clamped (clamps unreachable for real data; they
// only guarantee no i16 add overflow: 28000 + 4700 < 32767)
static __device__ __forceinline__ short q_i16(float v, float clampv) {
  return (short)__float2int_rn(fminf(fmaxf(v * SCALE, -clampv), clampv));
}

// ---------------- LayerNorm: one WAVE per row, i16(x1024) out ----------------
__global__ __launch_bounds__(256) void ln_kernel(const float* __restrict__ x,
                                                 const float* __restrict__ gamma,
                                                 const float* __restrict__ beta,
                                                 short* __restrict__ xn) {
  const int lane = threadIdx.x & 63;
  const int wv = threadIdx.x >> 6;
  const int row = blockIdx.x * 4 + wv;
  const float4* xr = (const float4*)(x + (size_t)row * F);
  float4 v[4];
  float s = 0.f;
#pragma unroll
  for (int j = 0; j < 4; ++j) {
    v[j] = xr[lane + 64 * j];
    s += v[j].x + v[j].y + v[j].z + v[j].w;
  }
#pragma unroll
  for (int off = 32; off; off >>= 1) s += __shfl_xor(s, off, 64);
  const float mu = s * (1.0f / F);
  float sq = 0.f;
#pragma unroll
  for (int j = 0; j < 4; ++j) {
    v[j].x -= mu; v[j].y -= mu; v[j].z -= mu; v[j].w -= mu;
    sq += v[j].x * v[j].x + v[j].y * v[j].y + v[j].z * v[j].z + v[j].w * v[j].w;
  }
#pragma unroll
  for (int off = 32; off; off >>= 1) sq += __shfl_xor(sq, off, 64);
  const float r = rsqrtf(sq * (1.0f / F) + 1e-5f);
  const float4* g4 = (const float4*)gamma;
  const float4* b4 = (const float4*)beta;
  s4* o = (s4*)(xn + (size_t)row * F);
#pragma unroll
  for (int j = 0; j < 4; ++j) {
    const int idx = lane + 64 * j;
    const float4 g = g4[idx];
    const float4 bb = b4[idx];
    s4 q;
    q[0] = q_i16(v[j].x * r * g.x + bb.x, 28000.f);
    q[1] = q_i16(v[j].y * r * g.y + bb.y, 28000.f);
    q[2] = q_i16(v[j].z * r * g.z + bb.z, 28000.f);
    q[3] = q_i16(v[j].w * r * g.w + bb.w, 28000.f);
    o[idx] = q;
  }
}

// ---------------- W: f32 -> i16(x1024) ----------------
__global__ __launch_bounds__(256) void cvt_kernel(const float* __restrict__ Wf,
                                                  short* __restrict__ Wq) {
  const int i = blockIdx.x * 256 + threadIdx.x;  // float4 index
  const float4 v = ((const float4*)Wf)[i];
  s4 q;
  q[0] = q_i16(v.x, 4700.f);
  q[1] = q_i16(v.y, 4700.f);
  q[2] = q_i16(v.z, 4700.f);
  q[3] = q_i16(v.w, 4700.f);
  ((s4*)Wq)[i] = q;
}

// ---------------- i16 packed tropical (max,+) GEMM: 1 instr/update ----------------
// Thread (tx,ty): rows ty*8..+7, cols tx*8..+7. acc[m][nn] = i16x2 covering cols
// {tx*8+2nn, +1}. Inner per k per (m,nn): v_pk_add_i16 (op_sel bcast) + v_pk_max_i16
// -> 2 instrs / 2 updates. LDS: 1 ds_read_b128 for A + 1 for B per k per thread.
// R4: TLP via split-K z=8 grid (8 blocks/CU = 8 waves/SIMD). launch_bounds kept at
// (256,4): R3's (256,8) capped VGPR at 32 < the 32-reg acc -> scratch spills
// (FETCH 36->142 MB, WRITE 32->215 MB). 48 VGPR naturally allows 10 waves/SIMD.
__global__ __launch_bounds__(256, 4) void trop_i(const short* __restrict__ A,
                                                 const short* __restrict__ Wm,
                                                 const float* __restrict__ bias,
                                                 short* __restrict__ dsts,
                                                 float* __restrict__ outf,
                                                 int ntiles, int totrows, int fuse) {
  __shared__ alignas(16) short As[2][BK][BM];  // transposed: As[buf][k][m]
  __shared__ alignas(16) short Bs[2][BK][BN];  // Bs[buf][k][n]

  const int tid = threadIdx.x;
  const int tx = tid & 15;
  const int ty = tid >> 4;
  const int row0 = blockIdx.y * BM;
  const int col0 = blockIdx.x * BN;
  const int kbase = blockIdx.z * ntiles * BK;

  // A stage: lane -> row (contiguous-in-m LDS writes: 2-way bank = free)
  const int ar = tid & 127;          // row 0..127
  const int ak = (tid >> 7) << 3;    // k offset 0 or 8
  // B stage: one k-row per 16 threads, contiguous 256B per k-row
  const int bk = tid >> 4;           // k-row 0..15
  const int bn = (tid & 15) << 3;    // col offset

  const short* Arow = A + (size_t)(row0 + ar) * F + kbase + ak;
  const short* Wrow = Wm + (size_t)(kbase + bk) * F + col0 + bn;

  s2 acc[8][4];
  const s2 ninf = {(short)-32768, (short)-32768};
#pragma unroll
  for (int m = 0; m < 8; ++m)
#pragma unroll
    for (int n = 0; n < 4; ++n) acc[m][n] = ninf;

  // stage tile 0 into buf 0
  {
    const s8 av = *(const s8*)Arow;
    const s8 bv = *(const s8*)Wrow;
#pragma unroll
    for (int j = 0; j < 8; ++j) As[0][ak + j][ar] = av[j];
    *(s8*)&Bs[0][bk][bn] = bv;
  }
  __syncthreads();

  for (int kt = 0; kt < ntiles; ++kt) {
    const int cur = kt & 1;
    s8 av, bv;
    if (kt + 1 < ntiles) {
      av = *(const s8*)(Arow + (kt + 1) * BK);
      bv = *(const s8*)(Wrow + (size_t)(kt + 1) * BK * F);
    }

#pragma unroll
    for (int k = 0; k < BK; ++k) {
      s8 a = *(const s8*)&As[cur][k][ty * 8];  // 8 rows
      s8 b = *(const s8*)&Bs[cur][k][tx * 8];  // 8 cols
      const s2* a2 = (const s2*)&a;
      const s2* b2 = (const s2*)&b;
#pragma unroll
      for (int m = 0; m < 8; ++m) {
        const s2 am = a2[m >> 1];
#pragma unroll
        for (int nn = 0; nn < 4; ++nn) {
          const s2 t = (m & 1) ? pk_add_bhi(am, b2[nn]) : pk_add_blo(am, b2[nn]);
          acc[m][nn] = pk_max_i16(acc[m][nn], t);
        }
      }
    }

    if (kt + 1 < ntiles) {
      const int nxt = cur ^ 1;
#pragma unroll
      for (int j = 0; j < 8; ++j) As[nxt][ak + j][ar] = av[j];
      *(s8*)&Bs[nxt][bk][bn] = bv;
      __syncthreads();
    }
  }

  if (fuse) {
    const float4 bv0 = *(const float4*)(bias + col0 + tx * 8);
    const float4 bv1 = *(const float4*)(bias + col0 + tx * 8 + 4);
#pragma unroll
    for (int m = 0; m < 8; ++m) {
      float* orow = outf + (size_t)(row0 + ty * 8 + m) * F + col0 + tx * 8;
      float4 o0, o1;
      o0.x = fmaxf((float)acc[m][0][0] * ISCALE, bv0.x);
      o0.y = fmaxf((float)acc[m][0][1] * ISCALE, bv0.y);
      o0.z = fmaxf((float)acc[m][1][0] * ISCALE, bv0.z);
      o0.w = fmaxf((float)acc[m][1][1] * ISCALE, bv0.w);
      o1.x = fmaxf((float)acc[m][2][0] * ISCALE, bv1.x);
      o1.y = fmaxf((float)acc[m][2][1] * ISCALE, bv1.y);
      o1.z = fmaxf((float)acc[m][3][0] * ISCALE, bv1.z);
      o1.w = fmaxf((float)acc[m][3][1] * ISCALE, bv1.w);
      *(float4*)orow = o0;
      *(float4*)(orow + 4) = o1;
    }
  } else {
    short* base = dsts + (size_t)blockIdx.z * totrows * F;
#pragma unroll
    for (int m = 0; m < 8; ++m) {
      short* orow = base + (size_t)(row0 + ty * 8 + m) * F + col0 + tx * 8;
      s8 o;
#pragma unroll
      for (int nn = 0; nn < 4; ++nn) {
        o[2 * nn] = acc[m][nn][0];
        o[2 * nn + 1] = acc[m][nn][1];
      }
      *(s8*)orow = o;
    }
  }
}

// ---------------- combine: out = max(NP i16 partials)/1024, then max(bias) ----------------
template <int NP>
__global__ __launch_bounds__(256) void combineNs(const short* __restrict__ p,
                                                 size_t plane,
                                                 const float* __restrict__ bias,
                                                 float* __restrict__ out) {
  const int i = blockIdx.x * 256 + threadIdx.x;  // s8 index
  s8 v = ((const s8*)p)[i];
  s2* vv = (s2*)&v;
#pragma unroll
  for (int q = 1; q < NP; ++q) {
    const s8 u = ((const s8*)(p + (size_t)q * plane))[i];
    const s2* uu = (const s2*)&u;
#pragma unroll
    for (int j = 0; j < 4; ++j) vv[j] = pk_max_i16(vv[j], uu[j]);
  }
  const int nb = (i & (F / 8 - 1)) * 8;
  const v4f bb0 = *(const v4f*)(bias + nb);
  const v4f bb1 = *(const v4f*)(bias + nb + 4);
  float4* o4 = (float4*)(out + (size_t)i * 8);
  float4 o0, o1;
  o0.x = fmaxf((float)v[0] * ISCALE, bb0.x);
  o0.y = fmaxf((float)v[1] * ISCALE, bb0.y);
  o0.z = fmaxf((float)v[2] * ISCALE, bb0.z);
  o0.w = fmaxf((float)v[3] * ISCALE, bb0.w);
  o1.x = fmaxf((float)v[4] * ISCALE, bb1.x);
  o1.y = fmaxf((float)v[5] * ISCALE, bb1.y);
  o1.z = fmaxf((float)v[6] * ISCALE, bb1.z);
  o1.w = fmaxf((float)v[7] * ISCALE, bb1.w);
  o4[0] = o0;
  o4[1] = o1;
}

extern "C" void kernel_launch(void* const* d_in, const int* in_sizes, int n_in,
                              void* d_out, int out_size, void* d_ws, size_t ws_size,
                              hipStream_t stream) {
  const float* x = (const float*)d_in[0];
  const float* Wm = (const float*)d_in[1];
  const float* bias = (const float*)d_in[2];
  const float* gamma = (const float*)d_in[3];
  const float* beta = (const float*)d_in[4];
  float* out = (float*)d_out;

  const int Brows = in_sizes[0] / F;  // 4096
  const size_t plane = (size_t)Brows * F;

  short* xnq = (short*)d_ws;                     // plane i16 (8 MB)
  short* Wq = xnq + plane;                       // F*F i16 (2 MB)
  short* parts = Wq + (size_t)F * F;             // up to 8 planes i16 (64 MB)

  ln_kernel<<<Brows / 4, 256, 0, stream>>>(x, gamma, beta, xnq);
  cvt_kernel<<<(F * F) / 1024, 256, 0, stream>>>(Wm, Wq);

  const size_t base2 = plane * 2 + (size_t)F * F * 2;
  const size_t need8 = base2 + 8 * plane * 2;
  const size_t need4 = base2 + 4 * plane * 2;
  const size_t need1 = base2;
  if (ws_size >= need8) {
    dim3 grid(F / BN, Brows / BM, 8);  // 2048 blocks = 8 blocks/CU = 32 waves/CU
    trop_i<<<grid, 256, 0, stream>>>(xnq, Wq, bias, parts, nullptr,
                                     (F / BK) / 8, Brows, 0);
    combineNs<8><<<(int)(plane / 2048), 256, 0, stream>>>(parts, plane, bias, out);
  } else if (ws_size >= need4) {
    dim3 grid(F / BN, Brows / BM, 4);  // 1024 blocks = 4 blocks/CU
    trop_i<<<grid, 256, 0, stream>>>(xnq, Wq, bias, parts, nullptr,
                                     (F / BK) / 4, Brows, 0);
    combineNs<4><<<(int)(plane / 2048), 256, 0, stream>>>(parts, plane, bias, out);
  } else if (ws_size >= need1) {
    dim3 grid(F / BN, Brows / BM, 1);
    trop_i<<<grid, 256, 0, stream>>>(xnq, Wq, bias, nullptr, out, F / BK, Brows, 1);
  }
}